// Round 6
// baseline (56.498 us; speedup 1.0000x reference)
//
#include <hip/hip_runtime.h>
#include <hip/hip_bf16.h>
#include <math.h>

// Shapes:
//   input [32,1024] f32; source_hids [2048,32,1024] f32 (256 MiB);
//   encoder_padding_mask [2048,32] bool; W_in [1024,1024]; W_out [1024,2048]
// Outputs flat: output [32,1024], beta [2048,32], alpha [2048,32]
//
// Exact simplifications (rounds 1-2):
//   alpha = p * exclusive_cumprod(1-p); beta = alpha.
//   f32: sigmoid(e)==1.0f exactly for e >~ 17.3 => (1-p)==0.0f => running
//   cumprod hits EXACT 0 => all later beta exactly 0 regardless of p.
//   => energy/scan only for s < CH=64; tails pre-zeroed; sequential fallback
//   (P ~ 1e-9) overwrites tail rows if a column hasn't collapsed. All exact.
//
// Round-6: cut L3 re-read amplification. GEMVs are 4-batch-stationary
// (W_in traffic 128->32 MB, W_out 128->64 MB); energy+scan+wc re-fused into
// one 32-block kernel (src chunk0 is L3-resident across replays); tail-fill
// rides in the xproj grid. 3 kernels total.

#define SRC_LEN 2048
#define BSZ     32
#define DIM     1024
#define CH      64
#define TAIL4   ((SRC_LEN - CH) * BSZ / 4)   // 15872 float4 per tail array
#define XPB     128                          // xproj blocks (512 waves)
#define FILLB   (TAIL4 / 256)                // 62 fill blocks

// ---------------- kernel 1: x = input @ W_in^T (4-batch register GEMV) + tail fill ----------------
__global__ __launch_bounds__(256) void k_xproj_fill(const float* __restrict__ input,
                                                    const float* __restrict__ W,
                                                    float* __restrict__ x,
                                                    float* __restrict__ beta_out,
                                                    float* __restrict__ alpha_out) {
    int bid = blockIdx.x;
    int t = threadIdx.x;
    if (bid < XPB) {
        int wid  = bid * 4 + (t >> 6);            // 0..511
        int lane = t & 63;
        int bq   = wid >> 6;                      // 0..7  (batch quad)
        int i0   = (wid & 63) * 16;               // 0..1008
        float4 in[4][4];
        #pragma unroll
        for (int q = 0; q < 4; ++q) {
            const float4* inp = (const float4*)(input + (size_t)(bq * 4 + q) * DIM);
            #pragma unroll
            for (int k = 0; k < 4; ++k) in[q][k] = inp[lane + 64 * k];
        }
        #pragma unroll 2
        for (int i = 0; i < 16; ++i) {
            const float4* wr = (const float4*)(W + (size_t)(i0 + i) * DIM);
            float4 wv[4];
            #pragma unroll
            for (int k = 0; k < 4; ++k) wv[k] = wr[lane + 64 * k];
            float acc[4] = {0.f, 0.f, 0.f, 0.f};
            #pragma unroll
            for (int k = 0; k < 4; ++k) {
                #pragma unroll
                for (int q = 0; q < 4; ++q)
                    acc[q] += wv[k].x * in[q][k].x + wv[k].y * in[q][k].y
                            + wv[k].z * in[q][k].z + wv[k].w * in[q][k].w;
            }
            #pragma unroll
            for (int off = 32; off; off >>= 1) {
                acc[0] += __shfl_down(acc[0], off);
                acc[1] += __shfl_down(acc[1], off);
                acc[2] += __shfl_down(acc[2], off);
                acc[3] += __shfl_down(acc[3], off);
            }
            if (lane == 0) {
                #pragma unroll
                for (int q = 0; q < 4; ++q)
                    x[(size_t)(bq * 4 + q) * DIM + i0 + i] = acc[q];
            }
        }
    } else {
        int i = (bid - XPB) * 256 + t;            // < TAIL4 by grid construction
        float4 z = {0.f, 0.f, 0.f, 0.f};
        ((float4*)(beta_out  + (size_t)CH * BSZ))[i] = z;
        ((float4*)(alpha_out + (size_t)CH * BSZ))[i] = z;
    }
}

// ---------------- kernel 2: fused energy(s<CH) + scan + wc (+ exact fallback) ----------------
// 32 blocks (one per b) x 1024 threads; src chunk0 is L3-hot across replays.
__global__ __launch_bounds__(1024) void k_attn(const float* __restrict__ src,
                                               const float* __restrict__ x,
                                               const unsigned char* __restrict__ mask,
                                               float* __restrict__ beta_out,
                                               float* __restrict__ alpha_out,
                                               float* __restrict__ wc) {
    int b = blockIdx.x;
    int t = threadIdx.x;
    int w = t >> 6, lane = t & 63;
    __shared__ __align__(16) float xs[DIM];
    __shared__ float e[CH];
    __shared__ float pb[CH];
    __shared__ int   snz;
    __shared__ float cstate;
    __shared__ float red[16];
    __shared__ float crun, bcur;

    for (int i = t; i < DIM; i += 1024) xs[i] = x[(size_t)b * DIM + i];
    __syncthreads();

    // energies: wave w owns rows {w, w+16, w+32, w+48}
    const float4* x4 = (const float4*)xs;
    #pragma unroll
    for (int r = 0; r < 4; ++r) {
        int s = w + 16 * r;
        const float4* row = (const float4*)(src + ((size_t)s * BSZ + b) * DIM);
        float acc = 0.f;
        #pragma unroll
        for (int it = 0; it < 4; ++it) {
            float4 v = row[it * 64 + lane];
            float4 c = x4[it * 64 + lane];
            acc += v.x * c.x + v.y * c.y + v.z * c.z + v.w * c.w;
        }
        #pragma unroll
        for (int off = 32; off; off >>= 1) acc += __shfl_down(acc, off);
        if (lane == 0) e[s] = acc;
    }
    __syncthreads();

    // wave 0: sigmoid + exclusive cumprod scan
    if (w == 0) {
        float ev = e[lane];
        if (mask[(size_t)lane * BSZ + b]) ev = -1e9f;
        float p  = 1.0f / (1.0f + expf(-ev));
        float om = 1.0f - p;
        float prod = om;
        #pragma unroll
        for (int off = 1; off < 64; off <<= 1) {
            float o = __shfl_up(prod, off);
            if (lane >= off) prod *= o;
        }
        float excl = __shfl_up(prod, 1);
        if (lane == 0) excl = 1.0f;
        float a = p * excl;
        beta_out[(size_t)lane * BSZ + b]  = a;
        alpha_out[(size_t)lane * BSZ + b] = a;
        pb[lane] = a;
        unsigned long long nz = __ballot(a != 0.0f);
        if (lane == 0) snz = (nz == 0ULL) ? 0 : (64 - __builtin_clzll(nz));
        if (lane == 63) cstate = prod;
    }
    __syncthreads();

    // weighted context over the nonzero prefix (rows L3-hot)
    float acc = 0.f;                       // thread t owns wc[b, t]
    int smax = snz;
    for (int s = 0; s < smax; ++s) {
        float wgt = pb[s];
        if (wgt != 0.0f) acc += wgt * src[((size_t)s * BSZ + b) * DIM + t];
    }

    // sequential fallback for a non-collapsed column (exact; ~never runs)
    if (cstate != 0.0f) {
        if (t == 0) crun = cstate;
        __syncthreads();
        for (int s = CH; s < SRC_LEN; ++s) {
            float v = src[((size_t)s * BSZ + b) * DIM + t];
            float part = v * xs[t];
            #pragma unroll
            for (int off = 32; off; off >>= 1) part += __shfl_down(part, off);
            if (lane == 0) red[w] = part;
            __syncthreads();
            if (t == 0) {
                float ev = 0.f;
                #pragma unroll
                for (int i = 0; i < 16; ++i) ev += red[i];
                if (mask[(size_t)s * BSZ + b]) ev = -1e9f;
                float p = 1.0f / (1.0f + expf(-ev));
                float a = p * crun;
                beta_out[(size_t)s * BSZ + b]  = a;
                alpha_out[(size_t)s * BSZ + b] = a;
                bcur = a;
                crun = crun * (1.0f - p);
            }
            __syncthreads();
            acc += bcur * v;
            if (crun == 0.0f) break;
        }
    }

    wc[(size_t)b * DIM + t] = acc;
}

// ---------------- kernel 3: out = tanh([wc, input] @ W_out^T) (4-batch register GEMV) ----------------
// 128 blocks x 256 thr = 512 waves; wave -> (batch quad, 16-wide o-chunk)
__global__ __launch_bounds__(256) void k_out(const float* __restrict__ wc,
                                             const float* __restrict__ input,
                                             const float* __restrict__ W,
                                             float* __restrict__ out) {
    int wid  = blockIdx.x * 4 + (threadIdx.x >> 6);   // 0..511
    int lane = threadIdx.x & 63;
    int bq   = wid >> 6;                              // 0..7
    int o0   = (wid & 63) * 16;                       // 0..1008
    float4 c[4][4], u[4][4];
    #pragma unroll
    for (int q = 0; q < 4; ++q) {
        const float4* wcp = (const float4*)(wc    + (size_t)(bq * 4 + q) * DIM);
        const float4* inp = (const float4*)(input + (size_t)(bq * 4 + q) * DIM);
        #pragma unroll
        for (int k = 0; k < 4; ++k) {
            c[q][k] = wcp[lane + 64 * k];
            u[q][k] = inp[lane + 64 * k];
        }
    }
    for (int i = 0; i < 16; ++i) {
        const float4* wr = (const float4*)(W + (size_t)(o0 + i) * 2 * DIM);
        float acc[4] = {0.f, 0.f, 0.f, 0.f};
        #pragma unroll
        for (int k = 0; k < 4; ++k) {
            float4 wv = wr[lane + 64 * k];            // pairs with wc part
            #pragma unroll
            for (int q = 0; q < 4; ++q)
                acc[q] += wv.x * c[q][k].x + wv.y * c[q][k].y
                        + wv.z * c[q][k].z + wv.w * c[q][k].w;
        }
        #pragma unroll
        for (int k = 0; k < 4; ++k) {
            float4 wv = wr[256 + lane + 64 * k];      // pairs with input part
            #pragma unroll
            for (int q = 0; q < 4; ++q)
                acc[q] += wv.x * u[q][k].x + wv.y * u[q][k].y
                        + wv.z * u[q][k].z + wv.w * u[q][k].w;
        }
        #pragma unroll
        for (int off = 32; off; off >>= 1) {
            acc[0] += __shfl_down(acc[0], off);
            acc[1] += __shfl_down(acc[1], off);
            acc[2] += __shfl_down(acc[2], off);
            acc[3] += __shfl_down(acc[3], off);
        }
        if (lane == 0) {
            #pragma unroll
            for (int q = 0; q < 4; ++q)
                out[(size_t)(bq * 4 + q) * DIM + o0 + i] = tanhf(acc[q]);
        }
    }
}

extern "C" void kernel_launch(void* const* d_in, const int* in_sizes, int n_in,
                              void* d_out, int out_size, void* d_ws, size_t ws_size,
                              hipStream_t stream) {
    const float* input = (const float*)d_in[0];
    const float* src   = (const float*)d_in[1];
    const unsigned char* mask = (const unsigned char*)d_in[2];
    const float* W_in  = (const float*)d_in[3];
    const float* W_out = (const float*)d_in[4];

    float* out_proj  = (float*)d_out;                 // [32,1024]
    float* beta_out  = out_proj + BSZ * DIM;          // [2048,32]
    float* alpha_out = beta_out + SRC_LEN * BSZ;      // [2048,32]

    float* ws = (float*)d_ws;
    float* x  = ws;                    // 32768 floats
    float* wc = x + BSZ * DIM;         // 32768 floats

    k_xproj_fill<<<XPB + FILLB, 256, 0, stream>>>(input, W_in, x, beta_out, alpha_out);
    k_attn<<<BSZ, 1024, 0, stream>>>(src, x, mask, beta_out, alpha_out, wc);
    k_out<<<128, 256, 0, stream>>>(wc, input, W_out, out_proj);
}

// Round 7
// 30.565 us; speedup vs baseline: 1.8484x; 1.8484x over previous
//
#include <hip/hip_runtime.h>
#include <hip/hip_bf16.h>
#include <math.h>

// Shapes:
//   input [32,1024] f32; source_hids [2048,32,1024] f32 (256 MiB);
//   encoder_padding_mask [2048,32] bool; W_in [1024,1024]; W_out [1024,2048]
// Outputs flat: output [32,1024], beta [2048,32], alpha [2048,32]
//
// Exact simplifications (rounds 1-2):
//   alpha = p * exclusive_cumprod(1-p); beta = alpha.
//   f32: sigmoid(e)==1.0f exactly for e >~ 17.3 => (1-p)==0.0f => running
//   cumprod hits EXACT 0 => all later beta exactly 0 regardless of p.
//   => energy/scan only for s < CH=64; tails pre-zeroed; sequential fallback
//   (P ~ 1e-9) overwrites tail rows if a column hasn't collapsed. All exact.
//
// Round-7: revert to R5 (proven 31.8 us — GEMVs are latency/parallelism-bound,
// NOT L2/L3-BW-bound; R6's batch-stationary blocking regressed 2x). Single
// change vs R5: k_out goes Q=2/1024 waves -> Q=1/2048 waves (same shape as the
// proven k_xproj: fewer live registers, more waves, deeper unroll).

#define SRC_LEN 2048
#define BSZ     32
#define DIM     1024
#define CH      64
#define TAIL4   ((SRC_LEN - CH) * BSZ / 4)   // 15872 float4 per tail array

// ---------------- kernel 1: x = input @ W_in^T (register GEMV) ----------------
// 512 blocks x 256 thr = 2048 waves; wave -> (b, 16-wide i-chunk)
__global__ __launch_bounds__(256) void k_xproj(const float* __restrict__ input,
                                               const float* __restrict__ W,
                                               float* __restrict__ x) {
    int wid  = blockIdx.x * 4 + (threadIdx.x >> 6);   // 0..2047
    int lane = threadIdx.x & 63;
    int b    = wid >> 6;                              // 0..31
    int i0   = (wid & 63) * 16;                       // 0..1008
    const float4* inp = (const float4*)(input + (size_t)b * DIM);
    float4 in[4];
    #pragma unroll
    for (int k = 0; k < 4; ++k) in[k] = inp[lane + 64 * k];
    #pragma unroll 4
    for (int i = 0; i < 16; ++i) {
        const float4* wr = (const float4*)(W + (size_t)(i0 + i) * DIM);
        float acc = 0.f;
        #pragma unroll
        for (int k = 0; k < 4; ++k) {
            float4 wv = wr[lane + 64 * k];
            acc += wv.x * in[k].x + wv.y * in[k].y + wv.z * in[k].z + wv.w * in[k].w;
        }
        #pragma unroll
        for (int off = 32; off; off >>= 1) acc += __shfl_down(acc, off);
        if (lane == 0) x[(size_t)b * DIM + i0 + i] = acc;
    }
}

// ---------------- kernel 2: energies (s<CH) + tail zero-fill ----------------
// blocks [0,512): 4 waves each, one (s,b) dot per wave (2048 dots).
// blocks [512,512+64): coalesced float4 zero-fill of beta/alpha tails.
__global__ __launch_bounds__(256) void k_energy_fill(const float* __restrict__ src,
                                                     const float* __restrict__ x,
                                                     float* __restrict__ energy,
                                                     float* __restrict__ beta_out,
                                                     float* __restrict__ alpha_out) {
    int bid = blockIdx.x;
    if (bid < 512) {
        int wid  = bid * 4 + (threadIdx.x >> 6);      // 0..2047
        int lane = threadIdx.x & 63;
        int s = wid >> 5, b = wid & (BSZ - 1);
        const float4* row = (const float4*)(src + ((size_t)s * BSZ + b) * DIM);
        const float4* xr  = (const float4*)(x + (size_t)b * DIM);
        float acc = 0.f;
        #pragma unroll
        for (int k = 0; k < 4; ++k) {
            float4 v = row[lane + 64 * k];
            float4 c = xr[lane + 64 * k];
            acc += v.x * c.x + v.y * c.y + v.z * c.z + v.w * c.w;
        }
        #pragma unroll
        for (int off = 32; off; off >>= 1) acc += __shfl_down(acc, off);
        if (lane == 0) energy[(size_t)s * BSZ + b] = acc;
    } else {
        int i = (bid - 512) * 256 + threadIdx.x;
        if (i < TAIL4) {
            float4 z = {0.f, 0.f, 0.f, 0.f};
            ((float4*)(beta_out  + (size_t)CH * BSZ))[i] = z;
            ((float4*)(alpha_out + (size_t)CH * BSZ))[i] = z;
        }
    }
}

// ---------------- kernel 3: scan + wc (+ exact sequential fallback) ----------------
// 32 blocks (one per b), 1024 threads; reads are L2/L3-hot.
__global__ __launch_bounds__(1024) void k_scan_wc(const float* __restrict__ src,
                                                  const float* __restrict__ x,
                                                  const unsigned char* __restrict__ mask,
                                                  const float* __restrict__ energy,
                                                  float* __restrict__ beta_out,
                                                  float* __restrict__ alpha_out,
                                                  float* __restrict__ wc) {
    int b = blockIdx.x;
    int t = threadIdx.x;
    int w = t >> 6, lane = t & 63;
    __shared__ float pb[CH];
    __shared__ int   snz;      // number of leading rows with beta != 0
    __shared__ float cstate;
    __shared__ float red[16];
    __shared__ float crun, bcur;
    __shared__ __align__(16) float xs[DIM];

    // wave 0: sigmoid + exclusive cumprod scan over s < CH
    if (w == 0) {
        float ev = energy[(size_t)lane * BSZ + b];
        if (mask[(size_t)lane * BSZ + b]) ev = -1e9f;
        float p  = 1.0f / (1.0f + expf(-ev));
        float om = 1.0f - p;
        float prod = om;
        #pragma unroll
        for (int off = 1; off < 64; off <<= 1) {
            float o = __shfl_up(prod, off);
            if (lane >= off) prod *= o;
        }
        float excl = __shfl_up(prod, 1);
        if (lane == 0) excl = 1.0f;
        float a = p * excl;
        beta_out[(size_t)lane * BSZ + b]  = a;
        alpha_out[(size_t)lane * BSZ + b] = a;
        pb[lane] = a;
        unsigned long long nz = __ballot(a != 0.0f);
        if (lane == 0) snz = (nz == 0ULL) ? 0 : (64 - __builtin_clzll(nz));
        if (lane == 63) cstate = prod;
    }
    __syncthreads();

    // weighted context over the nonzero prefix (rows cache-hot)
    float acc = 0.f;                       // thread t owns wc[b, t]
    int smax = snz;
    for (int s = 0; s < smax; ++s) {
        float wgt = pb[s];
        if (wgt != 0.0f) acc += wgt * src[((size_t)s * BSZ + b) * DIM + t];
    }

    // sequential fallback for a non-collapsed column (exact; ~never runs)
    if (cstate != 0.0f) {
        for (int i = t; i < DIM; i += 1024) xs[i] = x[(size_t)b * DIM + i];
        if (t == 0) crun = cstate;
        __syncthreads();
        for (int s = CH; s < SRC_LEN; ++s) {
            float v = src[((size_t)s * BSZ + b) * DIM + t];
            float part = v * xs[t];
            #pragma unroll
            for (int off = 32; off; off >>= 1) part += __shfl_down(part, off);
            if (lane == 0) red[w] = part;
            __syncthreads();
            if (t == 0) {
                float ev = 0.f;
                #pragma unroll
                for (int i = 0; i < 16; ++i) ev += red[i];
                if (mask[(size_t)s * BSZ + b]) ev = -1e9f;
                float p = 1.0f / (1.0f + expf(-ev));
                float a = p * crun;
                beta_out[(size_t)s * BSZ + b]  = a;
                alpha_out[(size_t)s * BSZ + b] = a;
                bcur = a;
                crun = crun * (1.0f - p);
            }
            __syncthreads();
            acc += bcur * v;
            if (crun == 0.0f) break;
        }
    }

    wc[(size_t)b * DIM + t] = acc;
}

// ---------------- kernel 4: out = tanh([wc, input] @ W_out^T) (register GEMV) ----------------
// 512 blocks x 256 thr = 2048 waves; wave -> (b, 16-wide o-chunk); Q=1.
__global__ __launch_bounds__(256) void k_out(const float* __restrict__ wc,
                                             const float* __restrict__ input,
                                             const float* __restrict__ W,
                                             float* __restrict__ out) {
    int wid  = blockIdx.x * 4 + (threadIdx.x >> 6);   // 0..2047
    int lane = threadIdx.x & 63;
    int b    = wid >> 6;                              // 0..31
    int o0   = (wid & 63) * 16;                       // 0..1008
    const float4* wcp = (const float4*)(wc    + (size_t)b * DIM);
    const float4* inp = (const float4*)(input + (size_t)b * DIM);
    float4 c[4], u[4];
    #pragma unroll
    for (int k = 0; k < 4; ++k) {
        c[k] = wcp[lane + 64 * k];
        u[k] = inp[lane + 64 * k];
    }
    #pragma unroll 4
    for (int i = 0; i < 16; ++i) {
        const float4* wr = (const float4*)(W + (size_t)(o0 + i) * 2 * DIM);
        float acc = 0.f;
        #pragma unroll
        for (int k = 0; k < 4; ++k) {
            float4 wv = wr[lane + 64 * k];            // pairs with wc part
            acc += wv.x * c[k].x + wv.y * c[k].y + wv.z * c[k].z + wv.w * c[k].w;
        }
        #pragma unroll
        for (int k = 0; k < 4; ++k) {
            float4 wv = wr[256 + lane + 64 * k];      // pairs with input part
            acc += wv.x * u[k].x + wv.y * u[k].y + wv.z * u[k].z + wv.w * u[k].w;
        }
        #pragma unroll
        for (int off = 32; off; off >>= 1) acc += __shfl_down(acc, off);
        if (lane == 0) out[(size_t)b * DIM + o0 + i] = tanhf(acc);
    }
}

extern "C" void kernel_launch(void* const* d_in, const int* in_sizes, int n_in,
                              void* d_out, int out_size, void* d_ws, size_t ws_size,
                              hipStream_t stream) {
    const float* input = (const float*)d_in[0];
    const float* src   = (const float*)d_in[1];
    const unsigned char* mask = (const unsigned char*)d_in[2];
    const float* W_in  = (const float*)d_in[3];
    const float* W_out = (const float*)d_in[4];

    float* out_proj  = (float*)d_out;                 // [32,1024]
    float* beta_out  = out_proj + BSZ * DIM;          // [2048,32]
    float* alpha_out = beta_out + SRC_LEN * BSZ;      // [2048,32]

    float* ws = (float*)d_ws;
    float* x      = ws;                    // 32768 floats
    float* wc     = x + BSZ * DIM;         // 32768 floats
    float* energy = wc + BSZ * DIM;        // 2048 floats

    k_xproj<<<512, 256, 0, stream>>>(input, W_in, x);
    k_energy_fill<<<512 + 64, 256, 0, stream>>>(src, x, energy, beta_out, alpha_out);
    k_scan_wc<<<BSZ, 1024, 0, stream>>>(src, x, mask, energy, beta_out, alpha_out, wc);
    k_out<<<512, 256, 0, stream>>>(wc, input, W_out, out_proj);
}